// Round 1
// baseline (13797.011 us; speedup 1.0000x reference)
//
#include <hip/hip_runtime.h>
#include <hip/hip_bf16.h>

// Problem constants (from reference)
#define NBLK   4
#define HDIM   256
#define NHEADS 8
#define RDIM   20
#define CDIM   128
#define PDIM   190
#define BDIM   2
#define FDIM   1024
#define NROWS  (BDIM*PDIM*CDIM)          // 48640 rows of HDIM
#define NF     ((size_t)NROWS*(size_t)HDIM) // 12,451,840 floats per activation buffer

__device__ __forceinline__ float gelu_tanh(float x){
    const float k0 = 0.7978845608028654f; // sqrt(2/pi)
    const float k1 = 0.044715f;
    return 0.5f*x*(1.0f + tanhf(k0*(x + k1*x*x*x)));
}

// ---------------------------------------------------------------------------
// Embedding + pairwise row-sum: x[b,p,c,:] = emb[tok[b,i_p,c]] + emb[tok[b,j_p,c]]
// ---------------------------------------------------------------------------
__global__ __launch_bounds__(256) void embed_kernel(
    const int* __restrict__ tokens, const float* __restrict__ emb,
    float* __restrict__ x)
{
    int n = blockIdx.x;            // (b*P + p)*C + c
    int h = threadIdx.x;
    int c  = n % CDIM;
    int bp = n / CDIM;
    int p  = bp % PDIM;
    int b  = bp / PDIM;
    // decode pair (i,j) from p (np.triu_indices order)
    int i = 0, rem = p;
    while (rem >= (RDIM - 1 - i)) { rem -= (RDIM - 1 - i); ++i; }
    int j = i + 1 + rem;
    int t1 = tokens[(b*RDIM + i)*CDIM + c];
    int t2 = tokens[(b*RDIM + j)*CDIM + c];
    x[(size_t)n*HDIM + h] = emb[t1*HDIM + h] + emb[t2*HDIM + h];
}

// ---------------------------------------------------------------------------
// LayerNorm over last dim (256). One row per block.
// ---------------------------------------------------------------------------
__global__ __launch_bounds__(256) void ln_kernel(
    const float* __restrict__ X, const float* __restrict__ g,
    const float* __restrict__ bta, float* __restrict__ Out)
{
    int n = blockIdx.x;
    int h = threadIdx.x;
    float v = X[(size_t)n*HDIM + h];
    float s1 = v, s2 = v*v;
    #pragma unroll
    for (int off = 1; off < 64; off <<= 1) {
        s1 += __shfl_xor(s1, off);
        s2 += __shfl_xor(s2, off);
    }
    __shared__ float red[2][4];
    int wave = h >> 6;
    if ((h & 63) == 0) { red[0][wave] = s1; red[1][wave] = s2; }
    __syncthreads();
    s1 = red[0][0] + red[0][1] + red[0][2] + red[0][3];
    s2 = red[1][0] + red[1][1] + red[1][2] + red[1][3];
    float mu  = s1 * (1.0f/HDIM);
    float var = s2 * (1.0f/HDIM) - mu*mu;
    float inv = rsqrtf(var + 1e-5f);
    Out[(size_t)n*HDIM + h] = (v - mu)*inv*g[h] + bta[h];
}

// ---------------------------------------------------------------------------
// Tiled fp32 GEMM: Out[n,m] (op)= A[n,k] @ W[k,m]
// 64x64 tile, BK=16, 256 threads, 4x4 micro-tile.
// EPI: 0 = store, 1 = gelu(acc+bias) store, 2 = Out += acc, 3 = Out += acc+bias
// Requires: rows%64==0 (grid.y*64 rows), M%64==0, K%16==0.
// ---------------------------------------------------------------------------
template<int EPI>
__global__ __launch_bounds__(256) void gemm_kernel(
    const float* __restrict__ A, const float* __restrict__ W,
    const float* __restrict__ bias, float* __restrict__ Out,
    int Kdim, int Mdim)
{
    __shared__ float As[64][17];   // [m][k], +1 pad
    __shared__ float Ws[16][64];   // [k][n]
    const int tid  = threadIdx.x;
    const int row0 = blockIdx.y * 64;
    const int n0   = blockIdx.x * 64;
    const int tm = tid >> 4, tn = tid & 15;
    const int ar = tid >> 2, akq = tid & 3;    // A: 64 rows x 4 float4
    const int wk = tid >> 4, wn = tid & 15;    // W: 16 rows x 16 float4

    float acc[4][4] = {};

    for (int k0 = 0; k0 < Kdim; k0 += 16) {
        float4 a4 = *(const float4*)(A + (size_t)(row0 + ar)*Kdim + k0 + akq*4);
        float4 w4 = *(const float4*)(W + (size_t)(k0 + wk)*Mdim + n0 + wn*4);
        __syncthreads();
        As[ar][akq*4+0] = a4.x; As[ar][akq*4+1] = a4.y;
        As[ar][akq*4+2] = a4.z; As[ar][akq*4+3] = a4.w;
        *(float4*)&Ws[wk][wn*4] = w4;
        __syncthreads();
        #pragma unroll
        for (int kk = 0; kk < 16; ++kk) {
            float a0 = As[tm*4+0][kk];
            float a1 = As[tm*4+1][kk];
            float a2 = As[tm*4+2][kk];
            float a3 = As[tm*4+3][kk];
            float4 w = *(const float4*)&Ws[kk][tn*4];
            acc[0][0] += a0*w.x; acc[0][1] += a0*w.y; acc[0][2] += a0*w.z; acc[0][3] += a0*w.w;
            acc[1][0] += a1*w.x; acc[1][1] += a1*w.y; acc[1][2] += a1*w.z; acc[1][3] += a1*w.w;
            acc[2][0] += a2*w.x; acc[2][1] += a2*w.y; acc[2][2] += a2*w.z; acc[2][3] += a2*w.w;
            acc[3][0] += a3*w.x; acc[3][1] += a3*w.y; acc[3][2] += a3*w.z; acc[3][3] += a3*w.w;
        }
    }

    #pragma unroll
    for (int i = 0; i < 4; ++i) {
        int row = row0 + tm*4 + i;
        #pragma unroll
        for (int j = 0; j < 4; ++j) {
            int col = n0 + tn*4 + j;
            float v = acc[i][j];
            if (EPI == 1 || EPI == 3) v += bias[col];
            if (EPI == 1) v = gelu_tanh(v);
            size_t idx = (size_t)row*Mdim + col;
            if (EPI == 2 || EPI == 3) Out[idx] += v;
            else                      Out[idx] = v;
        }
    }
}

// ---------------------------------------------------------------------------
// Multi-head attention over one axis. One block per (b, other, head).
// isRow=1: attend over p (L=190), other=c.  isRow=0: attend over c (L=128), other=p.
// Q,K,V are [NROWS,HDIM] projection buffers; O written same layout.
// ---------------------------------------------------------------------------
__global__ __launch_bounds__(256) void attn_kernel(
    const float* __restrict__ Q, const float* __restrict__ K,
    const float* __restrict__ V, float* __restrict__ O, int isRow)
{
    __shared__ float qs[PDIM*33];
    __shared__ float ks[PDIM*33];
    __shared__ float vs[PDIM*33];
    __shared__ float ps[4][192];

    int bid  = blockIdx.x;
    int head = bid % NHEADS;
    int L; size_t base, stride;
    if (isRow) {
        int c = (bid / NHEADS) % CDIM;
        int b = bid / (NHEADS*CDIM);
        L = PDIM;
        base   = ((size_t)(b*PDIM)*CDIM + c)*HDIM + head*32;
        stride = (size_t)CDIM*HDIM;
    } else {
        int p = (bid / NHEADS) % PDIM;
        int b = bid / (NHEADS*PDIM);
        L = CDIM;
        base   = ((size_t)(b*PDIM + p)*CDIM)*HDIM + head*32;
        stride = HDIM;
    }

    const int tid = threadIdx.x;
    for (int idx = tid; idx < L*32; idx += 256) {
        int p = idx >> 5, d = idx & 31;
        size_t gaddr = base + (size_t)p*stride + d;
        qs[p*33 + d] = Q[gaddr];
        ks[p*33 + d] = K[gaddr];
        vs[p*33 + d] = V[gaddr];
    }
    __syncthreads();

    const int wave = tid >> 6, lane = tid & 63;
    const float scale = 0.17677669529663687f; // 1/sqrt(32)
    const int Lh = (L + 1) >> 1;

    for (int p0 = wave; p0 < L; p0 += 4) {
        float s[3];
        #pragma unroll
        for (int t = 0; t < 3; ++t) {
            int qq = lane + t*64;
            float a = 0.f;
            if (qq < L) {
                #pragma unroll
                for (int d = 0; d < 32; ++d) a += qs[p0*33 + d]*ks[qq*33 + d];
            }
            s[t] = (qq < L) ? a*scale : -1e30f;
        }
        float m = fmaxf(fmaxf(s[0], s[1]), s[2]);
        #pragma unroll
        for (int off = 1; off < 64; off <<= 1) m = fmaxf(m, __shfl_xor(m, off));
        float e[3]; float sum = 0.f;
        #pragma unroll
        for (int t = 0; t < 3; ++t) {
            int qq = lane + t*64;
            e[t] = (qq < L) ? expf(s[t] - m) : 0.f;
            sum += e[t];
        }
        #pragma unroll
        for (int off = 1; off < 64; off <<= 1) sum += __shfl_xor(sum, off);
        float inv = 1.0f / sum;
        #pragma unroll
        for (int t = 0; t < 3; ++t) {
            int qq = lane + t*64;
            if (qq < L) ps[wave][qq] = e[t]*inv;
        }
        __builtin_amdgcn_wave_barrier(); // order LDS writes before cross-lane reads (wave-synchronous)

        int half = lane >> 5, d = lane & 31;
        int qlo = half ? Lh : 0, qhi = half ? L : Lh;
        float acc = 0.f;
        for (int qq = qlo; qq < qhi; ++qq) acc += ps[wave][qq]*vs[qq*33 + d];
        acc += __shfl_xor(acc, 32);
        if (lane < 32) O[base + (size_t)p0*stride + d] = acc;
    }
}

// ---------------------------------------------------------------------------
// Head GEMV: y[n] = T[n,:1024] . w + bias  (one wave per row)
// ---------------------------------------------------------------------------
__global__ __launch_bounds__(256) void gemv_head(
    const float* __restrict__ T, const float* __restrict__ w,
    const float* __restrict__ bias, float* __restrict__ y)
{
    int row  = blockIdx.x*4 + (threadIdx.x >> 6);
    int lane = threadIdx.x & 63;
    const float* t = T + (size_t)row*FDIM;
    float acc = 0.f;
    for (int j = lane; j < FDIM; j += 64) acc += t[j]*w[j];
    #pragma unroll
    for (int off = 1; off < 64; off <<= 1) acc += __shfl_xor(acc, off);
    if (lane == 0) y[row] = acc + bias[0];
}

// ---------------------------------------------------------------------------
// Final: out[b,p] = sum_c y[b,p,c]*uW[c] + ub
// ---------------------------------------------------------------------------
__global__ __launch_bounds__(128) void final_kernel(
    const float* __restrict__ y, const float* __restrict__ uW,
    const float* __restrict__ ub, float* __restrict__ out)
{
    int bp = blockIdx.x;       // 0..379
    int c  = threadIdx.x;      // 0..127
    float v = y[(size_t)bp*CDIM + c]*uW[c];
    #pragma unroll
    for (int off = 1; off < 64; off <<= 1) v += __shfl_xor(v, off);
    __shared__ float r[2];
    if ((c & 63) == 0) r[c >> 6] = v;
    __syncthreads();
    if (c == 0) out[bp] = r[0] + r[1] + ub[0];
}

// ---------------------------------------------------------------------------
extern "C" void kernel_launch(void* const* d_in, const int* in_sizes, int n_in,
                              void* d_out, int out_size, void* d_ws, size_t ws_size,
                              hipStream_t stream)
{
    const int*   tokens = (const int*)  d_in[0];
    const float* emb    = (const float*)d_in[1];
    const float* ln1_g  = (const float*)d_in[2];
    const float* ln1_b  = (const float*)d_in[3];
    const float* rWq    = (const float*)d_in[4];
    const float* rWk    = (const float*)d_in[5];
    const float* rWv    = (const float*)d_in[6];
    const float* rWo    = (const float*)d_in[7];
    const float* ln2_g  = (const float*)d_in[8];
    const float* ln2_b  = (const float*)d_in[9];
    const float* cWq    = (const float*)d_in[10];
    const float* cWk    = (const float*)d_in[11];
    const float* cWv    = (const float*)d_in[12];
    const float* cWo    = (const float*)d_in[13];
    const float* ln3_g  = (const float*)d_in[14];
    const float* ln3_b  = (const float*)d_in[15];
    const float* fW1    = (const float*)d_in[16];
    const float* fb1    = (const float*)d_in[17];
    const float* fW2    = (const float*)d_in[18];
    const float* fb2    = (const float*)d_in[19];
    const float* pW1    = (const float*)d_in[20];
    const float* pb1    = (const float*)d_in[21];
    const float* pW2    = (const float*)d_in[22];
    const float* pb2    = (const float*)d_in[23];
    const float* uW     = (const float*)d_in[24];
    const float* ub     = (const float*)d_in[25];

    float* ws = (float*)d_ws;
    float* x  = ws;            // [NROWS, 256]
    float* h  = ws + 1*NF;     // [NROWS, 256] (also head intermediate [NROWS,1024] spanning h..v)
    float* q  = ws + 2*NF;     // [NROWS, 256] (also FFN intermediate chunk [24320,1024] spanning q..k)
    float* k  = ws + 3*NF;
    float* v  = ws + 4*NF;
    float* y  = ws + 5*NF;     // [NROWS]
    // total ws use: 5*NF + NROWS floats ~= 249.3 MB

    const int HH = HDIM*HDIM;          // 65536
    const int HF = HDIM*FDIM;          // 262144
    const dim3 g256(4, NROWS/64);      // M=256 GEMMs over all rows (760 row tiles)
    const dim3 gF1(16, (NROWS/2)/64);  // M=1024 FFN chunk (380 row tiles)
    const dim3 gF2(4,  (NROWS/2)/64);

    embed_kernel<<<NROWS, 256, 0, stream>>>(tokens, emb, x);

    for (int i = 0; i < NBLK; ++i) {
        // ---- row attention (over pair axis) ----
        ln_kernel<<<NROWS, 256, 0, stream>>>(x, ln1_g + i*HDIM, ln1_b + i*HDIM, h);
        gemm_kernel<0><<<g256, 256, 0, stream>>>(h, rWq + (size_t)i*HH, nullptr, q, HDIM, HDIM);
        gemm_kernel<0><<<g256, 256, 0, stream>>>(h, rWk + (size_t)i*HH, nullptr, k, HDIM, HDIM);
        gemm_kernel<0><<<g256, 256, 0, stream>>>(h, rWv + (size_t)i*HH, nullptr, v, HDIM, HDIM);
        attn_kernel<<<BDIM*CDIM*NHEADS, 256, 0, stream>>>(q, k, v, h, 1);
        gemm_kernel<2><<<g256, 256, 0, stream>>>(h, rWo + (size_t)i*HH, nullptr, x, HDIM, HDIM);

        // ---- column attention ----
        ln_kernel<<<NROWS, 256, 0, stream>>>(x, ln2_g + i*HDIM, ln2_b + i*HDIM, h);
        gemm_kernel<0><<<g256, 256, 0, stream>>>(h, cWq + (size_t)i*HH, nullptr, q, HDIM, HDIM);
        gemm_kernel<0><<<g256, 256, 0, stream>>>(h, cWk + (size_t)i*HH, nullptr, k, HDIM, HDIM);
        gemm_kernel<0><<<g256, 256, 0, stream>>>(h, cWv + (size_t)i*HH, nullptr, v, HDIM, HDIM);
        attn_kernel<<<BDIM*PDIM*NHEADS, 256, 0, stream>>>(q, k, v, h, 0);
        gemm_kernel<2><<<g256, 256, 0, stream>>>(h, cWo + (size_t)i*HH, nullptr, x, HDIM, HDIM);

        // ---- FFN (chunked x2 so intermediate fits in q..k region) ----
        ln_kernel<<<NROWS, 256, 0, stream>>>(x, ln3_g + i*HDIM, ln3_b + i*HDIM, h);
        for (int ch = 0; ch < 2; ++ch) {
            const float* hA = h + (size_t)ch*(NROWS/2)*HDIM;
            float*       xC = x + (size_t)ch*(NROWS/2)*HDIM;
            gemm_kernel<1><<<gF1, 256, 0, stream>>>(hA, fW1 + (size_t)i*HF, fb1 + i*FDIM, q, HDIM, FDIM);
            gemm_kernel<3><<<gF2, 256, 0, stream>>>(q, fW2 + (size_t)i*HF, fb2 + i*HDIM, xC, FDIM, HDIM);
        }
    }

    // ---- head: t = gelu(x@pW1+pb1) [NROWS,1024] in h..v; y = t@pW2+pb2; out = y@uW+ub
    gemm_kernel<1><<<dim3(16, NROWS/64), 256, 0, stream>>>(x, pW1, pb1, h, HDIM, FDIM);
    gemv_head<<<NROWS/4, 256, 0, stream>>>(h, pW2, pb2, y);
    final_kernel<<<BDIM*PDIM, 128, 0, stream>>>(y, uW, ub, (float*)d_out);
}

// Round 2
// 8613.173 us; speedup vs baseline: 1.6018x; 1.6018x over previous
//
#include <hip/hip_runtime.h>
#include <hip/hip_bf16.h>
#include <stdint.h>

#define NBLK   4
#define HDIM   256
#define NHEADS 8
#define RDIM   20
#define CDIM   128
#define PDIM   190
#define BDIM   2
#define FDIM   1024
#define NROWS  (BDIM*PDIM*CDIM)             // 48640
#define NF     ((size_t)NROWS*(size_t)HDIM) // 12,451,840
#define HROWS  (NROWS/2)                    // 24320

typedef __attribute__((ext_vector_type(8))) short bf16x8;
typedef __attribute__((ext_vector_type(4))) float f32x4;

__device__ __forceinline__ short f2b(float f){
    uint32_t u = __float_as_uint(f);
    u += 0x7fff + ((u >> 16) & 1);          // RNE
    return (short)(u >> 16);
}
__device__ __forceinline__ float b2f(short s){
    return __uint_as_float(((uint32_t)(uint16_t)s) << 16);
}
__device__ __forceinline__ float gelu_tanh(float x){
    const float k0 = 0.7978845608028654f;
    const float k1 = 0.044715f;
    return 0.5f*x*(1.0f + tanhf(k0*(x + k1*x*x*x)));
}
__device__ __forceinline__ void async16(const void* g, void* l){
    __builtin_amdgcn_global_load_lds(
        (const __attribute__((address_space(1))) void*)g,
        (__attribute__((address_space(3))) void*)l, 16, 0, 0);
}

// ---------------------------------------------------------------------------
// Embedding + pairwise row-sum (fp32 residual init)
// ---------------------------------------------------------------------------
__global__ __launch_bounds__(256) void embed_kernel(
    const int* __restrict__ tokens, const float* __restrict__ emb,
    float* __restrict__ x)
{
    int n = blockIdx.x;
    int h = threadIdx.x;
    int c  = n % CDIM;
    int bp = n / CDIM;
    int p  = bp % PDIM;
    int b  = bp / PDIM;
    int i = 0, rem = p;
    while (rem >= (RDIM - 1 - i)) { rem -= (RDIM - 1 - i); ++i; }
    int j = i + 1 + rem;
    int t1 = tokens[(b*RDIM + i)*CDIM + c];
    int t2 = tokens[(b*RDIM + j)*CDIM + c];
    x[(size_t)n*HDIM + h] = emb[t1*HDIM + h] + emb[t2*HDIM + h];
}

// ---------------------------------------------------------------------------
// LayerNorm fp32 -> bf16 output (GEMM A operand)
// ---------------------------------------------------------------------------
__global__ __launch_bounds__(256) void ln_kernel(
    const float* __restrict__ X, const float* __restrict__ g,
    const float* __restrict__ bta, short* __restrict__ Out)
{
    int n = blockIdx.x;
    int h = threadIdx.x;
    float v = X[(size_t)n*HDIM + h];
    float s1 = v, s2 = v*v;
    #pragma unroll
    for (int off = 1; off < 64; off <<= 1) {
        s1 += __shfl_xor(s1, off);
        s2 += __shfl_xor(s2, off);
    }
    __shared__ float red[2][4];
    int wave = h >> 6;
    if ((h & 63) == 0) { red[0][wave] = s1; red[1][wave] = s2; }
    __syncthreads();
    s1 = red[0][0] + red[0][1] + red[0][2] + red[0][3];
    s2 = red[1][0] + red[1][1] + red[1][2] + red[1][3];
    float mu  = s1 * (1.0f/HDIM);
    float var = s2 * (1.0f/HDIM) - mu*mu;
    float inv = rsqrtf(var + 1e-5f);
    Out[(size_t)n*HDIM + h] = f2b((v - mu)*inv*g[h] + bta[h]);
}

// ---------------------------------------------------------------------------
// fp32 -> bf16 convert (head input)
// ---------------------------------------------------------------------------
__global__ __launch_bounds__(256) void cvt4_kernel(
    const float* __restrict__ in, short* __restrict__ out)
{
    size_t i = (size_t)blockIdx.x*256 + threadIdx.x;
    float4 f = ((const float4*)in)[i];
    short4 s;
    s.x = f2b(f.x); s.y = f2b(f.y); s.z = f2b(f.z); s.w = f2b(f.w);
    ((short4*)out)[i] = s;
}

// ---------------------------------------------------------------------------
// Weight transpose+convert: in f32 [K][M] -> out bf16 [M][K]
// grid (M/32, K/32, nz); per-z strides inz/outz (elements)
// ---------------------------------------------------------------------------
__global__ __launch_bounds__(256) void tconv_kernel(
    const float* __restrict__ in, short* __restrict__ out,
    int K, int M, size_t inz, size_t outz)
{
    __shared__ float t[32][33];
    in  += (size_t)blockIdx.z * inz;
    out += (size_t)blockIdx.z * outz;
    int m0 = blockIdx.x*32, k0 = blockIdx.y*32;
    int r = threadIdx.x >> 5, c = threadIdx.x & 31;
    #pragma unroll
    for (int i = 0; i < 4; ++i)
        t[r + i*8][c] = in[(size_t)(k0 + r + i*8)*M + m0 + c];
    __syncthreads();
    #pragma unroll
    for (int i = 0; i < 4; ++i) {
        int rr = r + i*8;
        out[(size_t)(m0 + rr)*K + k0 + c] = f2b(t[c][rr]);
    }
}

// ---------------------------------------------------------------------------
// bf16 MFMA GEMM (m97 structure): Out = A[rows,K] @ Wt[M,K]^T
// 128x128 tile, BK=32, 256 thr = 4 waves, each wave 64x64 via 4x4 16x16x32 frags.
// EPI 0: QKV split store bf16 (M=768 -> OB0/OB1/OB2 [rows][256])
// EPI 1: OutF[rows][256] += acc
// EPI 2: OB0[rows][M] = bf16(gelu(acc + bias))
// EPI 3: OutF[rows][256] += acc + bias
// ---------------------------------------------------------------------------
template<int EPI>
__global__ __launch_bounds__(256) void mgemm_kernel(
    const short* __restrict__ A, const short* __restrict__ Wt,
    const float* __restrict__ bias,
    float* __restrict__ OutF,
    short* __restrict__ OB0, short* __restrict__ OB1, short* __restrict__ OB2,
    int K, int M)
{
    __shared__ short As[128*32];
    __shared__ short Bs[128*32];
    const int tid  = threadIdx.x;
    const int lane = tid & 63, wid = tid >> 6;
    const int wr = wid >> 1, wc = wid & 1;
    const int row0 = blockIdx.y * 128, col0 = blockIdx.x * 128;

    f32x4 acc[4][4] = {};

    const int b_lo = wid*1024 + lane*16;      // byte offset in 8KB tile, iter 0

    for (int k0 = 0; k0 < K; k0 += 32) {
        __syncthreads();                      // readers of prev tile done
        #pragma unroll
        for (int it = 0; it < 2; ++it) {
            int b  = b_lo + it*4096;
            int r  = b >> 6;                  // tile row (64B per row)
            int cb = b & 63;                  // byte within row
            const char* ga = (const char*)A  + ((size_t)(row0 + r)*K + k0)*2 + cb;
            const char* gb = (const char*)Wt + ((size_t)(col0 + r)*K + k0)*2 + cb;
            async16(ga, (char*)As + (size_t)(wid*1024 + it*4096));
            async16(gb, (char*)Bs + (size_t)(wid*1024 + it*4096));
        }
        __syncthreads();                      // compiler drains vmcnt before barrier

        bf16x8 af[4], bfr[4];
        #pragma unroll
        for (int m = 0; m < 4; ++m)
            af[m] = *(const bf16x8*)(As + ((wr*64 + m*16 + (lane & 15))*32 + (lane >> 4)*8));
        #pragma unroll
        for (int n = 0; n < 4; ++n)
            bfr[n] = *(const bf16x8*)(Bs + ((wc*64 + n*16 + (lane & 15))*32 + (lane >> 4)*8));
        #pragma unroll
        for (int m = 0; m < 4; ++m)
            #pragma unroll
            for (int n = 0; n < 4; ++n)
                acc[m][n] = __builtin_amdgcn_mfma_f32_16x16x32_bf16(af[m], bfr[n], acc[m][n], 0, 0, 0);
    }

    // D layout: row = (lane>>4)*4 + reg, col = lane&15
    const int rb  = row0 + wr*64 + ((lane >> 4) << 2);
    const int cb0 = col0 + wc*64 + (lane & 15);
    #pragma unroll
    for (int m = 0; m < 4; ++m) {
        #pragma unroll
        for (int n = 0; n < 4; ++n) {
            int col = cb0 + n*16;
            #pragma unroll
            for (int r = 0; r < 4; ++r) {
                int row = rb + m*16 + r;
                float vv = acc[m][n][r];
                if (EPI == 0) {
                    int sec = col >> 8, cc = col & 255;
                    short* o = (sec == 0) ? OB0 : ((sec == 1) ? OB1 : OB2);
                    o[(size_t)row*HDIM + cc] = f2b(vv);
                } else if (EPI == 1) {
                    OutF[(size_t)row*HDIM + col] += vv;
                } else if (EPI == 2) {
                    OB0[(size_t)row*M + col] = f2b(gelu_tanh(vv + bias[col]));
                } else {
                    OutF[(size_t)row*HDIM + col] += vv + bias[col];
                }
            }
        }
    }
}

// ---------------------------------------------------------------------------
// Attention (fp32 math, bf16 in/out). One block per (b, other, head).
// ---------------------------------------------------------------------------
__global__ __launch_bounds__(256) void attn_kernel(
    const short* __restrict__ Q, const short* __restrict__ K,
    const short* __restrict__ V, short* __restrict__ O, int isRow)
{
    __shared__ float qs[PDIM*33];
    __shared__ float ks[PDIM*33];
    __shared__ float vs[PDIM*33];
    __shared__ float ps[4][192];

    int bid  = blockIdx.x;
    int head = bid % NHEADS;
    int L; size_t base, stride;
    if (isRow) {
        int c = (bid / NHEADS) % CDIM;
        int b = bid / (NHEADS*CDIM);
        L = PDIM;
        base   = ((size_t)(b*PDIM)*CDIM + c)*HDIM + head*32;
        stride = (size_t)CDIM*HDIM;
    } else {
        int p = (bid / NHEADS) % PDIM;
        int b = bid / (NHEADS*PDIM);
        L = CDIM;
        base   = ((size_t)(b*PDIM + p)*CDIM)*HDIM + head*32;
        stride = HDIM;
    }

    const int tid = threadIdx.x;
    for (int idx = tid; idx < L*8; idx += 256) {
        int p = idx >> 3, dq = (idx & 7)*4;
        size_t g = base + (size_t)p*stride + dq;
        short4 a = *(const short4*)(Q + g);
        short4 b = *(const short4*)(K + g);
        short4 c = *(const short4*)(V + g);
        float* qd = &qs[p*33 + dq];
        float* kd = &ks[p*33 + dq];
        float* vd = &vs[p*33 + dq];
        qd[0]=b2f(a.x); qd[1]=b2f(a.y); qd[2]=b2f(a.z); qd[3]=b2f(a.w);
        kd[0]=b2f(b.x); kd[1]=b2f(b.y); kd[2]=b2f(b.z); kd[3]=b2f(b.w);
        vd[0]=b2f(c.x); vd[1]=b2f(c.y); vd[2]=b2f(c.z); vd[3]=b2f(c.w);
    }
    __syncthreads();

    const int wave = tid >> 6, lane = tid & 63;
    const float scale = 0.17677669529663687f; // 1/sqrt(32)
    const int Lh = (L + 1) >> 1;

    for (int p0 = wave; p0 < L; p0 += 4) {
        float qr[32];
        #pragma unroll
        for (int d = 0; d < 32; ++d) qr[d] = qs[p0*33 + d];

        float s[3];
        #pragma unroll
        for (int t = 0; t < 3; ++t) {
            int qq = lane + t*64;
            float a = 0.f;
            if (qq < L) {
                #pragma unroll
                for (int d = 0; d < 32; ++d) a += qr[d]*ks[qq*33 + d];
            }
            s[t] = (qq < L) ? a*scale : -1e30f;
        }
        float m = fmaxf(fmaxf(s[0], s[1]), s[2]);
        #pragma unroll
        for (int off = 1; off < 64; off <<= 1) m = fmaxf(m, __shfl_xor(m, off));
        float e[3]; float sum = 0.f;
        #pragma unroll
        for (int t = 0; t < 3; ++t) {
            int qq = lane + t*64;
            e[t] = (qq < L) ? expf(s[t] - m) : 0.f;
            sum += e[t];
        }
        #pragma unroll
        for (int off = 1; off < 64; off <<= 1) sum += __shfl_xor(sum, off);
        float inv = 1.0f / sum;
        #pragma unroll
        for (int t = 0; t < 3; ++t) {
            int qq = lane + t*64;
            if (qq < L) ps[wave][qq] = e[t]*inv;
        }
        __builtin_amdgcn_wave_barrier();

        int half = lane >> 5, d = lane & 31;
        int qlo = half ? Lh : 0, qhi = half ? L : Lh;
        float acc = 0.f;
        for (int qq = qlo; qq < qhi; ++qq) acc += ps[wave][qq]*vs[qq*33 + d];
        acc += __shfl_xor(acc, 32);
        if (lane < 32) O[base + (size_t)p0*stride + d] = f2b(acc);
    }
}

// ---------------------------------------------------------------------------
// Head GEMV on bf16 intermediate: y[n] = T[n,:1024].w + bias
// ---------------------------------------------------------------------------
__global__ __launch_bounds__(256) void gemv_head(
    const short* __restrict__ T, const float* __restrict__ w,
    const float* __restrict__ bias, float* __restrict__ y)
{
    int row  = blockIdx.x*4 + (threadIdx.x >> 6);
    int lane = threadIdx.x & 63;
    const short* t = T + (size_t)row*FDIM;
    float acc = 0.f;
    #pragma unroll
    for (int it = 0; it < 4; ++it) {
        int ci = it*64 + lane;
        short4 tv = *(const short4*)(t + ci*4);
        float4 wv = *(const float4*)(w + ci*4);
        acc += b2f(tv.x)*wv.x + b2f(tv.y)*wv.y + b2f(tv.z)*wv.z + b2f(tv.w)*wv.w;
    }
    #pragma unroll
    for (int off = 1; off < 64; off <<= 1) acc += __shfl_xor(acc, off);
    if (lane == 0) y[row] = acc + bias[0];
}

__global__ __launch_bounds__(128) void final_kernel(
    const float* __restrict__ y, const float* __restrict__ uW,
    const float* __restrict__ ub, float* __restrict__ out)
{
    int bp = blockIdx.x;
    int c  = threadIdx.x;
    float v = y[(size_t)bp*CDIM + c]*uW[c];
    #pragma unroll
    for (int off = 1; off < 64; off <<= 1) v += __shfl_xor(v, off);
    __shared__ float r[2];
    if ((c & 63) == 0) r[c >> 6] = v;
    __syncthreads();
    if (c == 0) out[bp] = r[0] + r[1] + ub[0];
}

// ---------------------------------------------------------------------------
extern "C" void kernel_launch(void* const* d_in, const int* in_sizes, int n_in,
                              void* d_out, int out_size, void* d_ws, size_t ws_size,
                              hipStream_t stream)
{
    const int*   tokens = (const int*)  d_in[0];
    const float* emb    = (const float*)d_in[1];
    const float* ln1_g  = (const float*)d_in[2];
    const float* ln1_b  = (const float*)d_in[3];
    const float* rWq    = (const float*)d_in[4];
    const float* rWk    = (const float*)d_in[5];
    const float* rWv    = (const float*)d_in[6];
    const float* rWo    = (const float*)d_in[7];
    const float* ln2_g  = (const float*)d_in[8];
    const float* ln2_b  = (const float*)d_in[9];
    const float* cWq    = (const float*)d_in[10];
    const float* cWk    = (const float*)d_in[11];
    const float* cWv    = (const float*)d_in[12];
    const float* cWo    = (const float*)d_in[13];
    const float* ln3_g  = (const float*)d_in[14];
    const float* ln3_b  = (const float*)d_in[15];
    const float* fW1    = (const float*)d_in[16];
    const float* fb1    = (const float*)d_in[17];
    const float* fW2    = (const float*)d_in[18];
    const float* fb2    = (const float*)d_in[19];
    const float* pW1    = (const float*)d_in[20];
    const float* pb1    = (const float*)d_in[21];
    const float* pW2    = (const float*)d_in[22];
    const float* pb2    = (const float*)d_in[23];
    const float* uW     = (const float*)d_in[24];
    const float* ub     = (const float*)d_in[25];

    // ---- workspace layout ----
    float* x  = (float*)d_ws;               // NF f32
    short* q  = (short*)(x + NF);           // NF bf16   (also FFN/head intermediate [HROWS][1024])
    short* k  = q + NF;                     // NF bf16
    short* v  = k + NF;                     // NF bf16
    short* hb = v + NF;                     // NF bf16   (LN out / attn out / head input)
    float* y  = (float*)(hb + NF);          // NROWS f32
    short* wts = (short*)(y + NROWS);       // bf16 transposed weights
    short* w_rqkv = wts;                    // 4 x [768][256]
    short* w_cqkv = w_rqkv + 4*768*256;
    short* w_ro   = w_cqkv + 4*768*256;     // 4 x [256][256]
    short* w_co   = w_ro   + 4*256*256;
    short* w_f1   = w_co   + 4*256*256;     // 4 x [1024][256]
    short* w_f2   = w_f1   + (size_t)4*1024*256;  // 4 x [256][1024]
    short* w_p1   = w_f2   + (size_t)4*1024*256;  // [1024][256]
    short* tb = q;                          // FFN/head intermediate [HROWS][1024] bf16

    const size_t HH = 65536, HF = 262144, QZ = 768*256;

    // ---- weight prep (bf16, transposed, QKV packed) ----
    tconv_kernel<<<dim3(8,8,NBLK),   256, 0, stream>>>(rWq, w_rqkv,          256, 256,  HH, QZ);
    tconv_kernel<<<dim3(8,8,NBLK),   256, 0, stream>>>(rWk, w_rqkv + 65536,  256, 256,  HH, QZ);
    tconv_kernel<<<dim3(8,8,NBLK),   256, 0, stream>>>(rWv, w_rqkv + 131072, 256, 256,  HH, QZ);
    tconv_kernel<<<dim3(8,8,NBLK),   256, 0, stream>>>(rWo, w_ro,            256, 256,  HH, HH);
    tconv_kernel<<<dim3(8,8,NBLK),   256, 0, stream>>>(cWq, w_cqkv,          256, 256,  HH, QZ);
    tconv_kernel<<<dim3(8,8,NBLK),   256, 0, stream>>>(cWk, w_cqkv + 65536,  256, 256,  HH, QZ);
    tconv_kernel<<<dim3(8,8,NBLK),   256, 0, stream>>>(cWv, w_cqkv + 131072, 256, 256,  HH, QZ);
    tconv_kernel<<<dim3(8,8,NBLK),   256, 0, stream>>>(cWo, w_co,            256, 256,  HH, HH);
    tconv_kernel<<<dim3(32,8,NBLK),  256, 0, stream>>>(fW1, w_f1,            256, 1024, HF, HF);
    tconv_kernel<<<dim3(8,32,NBLK),  256, 0, stream>>>(fW2, w_f2,            1024, 256, HF, HF);
    tconv_kernel<<<dim3(32,8,1),     256, 0, stream>>>(pW1, w_p1,            256, 1024, HF, HF);

    embed_kernel<<<NROWS, 256, 0, stream>>>(tokens, emb, x);

    const dim3 gQKV(6, NROWS/128);   // M=768
    const dim3 gO(2, NROWS/128);     // M=256
    const dim3 gF1(8, HROWS/128);    // M=1024, half rows
    const dim3 gF2(2, HROWS/128);    // M=256,  half rows

    for (int i = 0; i < NBLK; ++i) {
        // ---- row attention (pair axis) ----
        ln_kernel<<<NROWS, 256, 0, stream>>>(x, ln1_g + i*HDIM, ln1_b + i*HDIM, hb);
        mgemm_kernel<0><<<gQKV, 256, 0, stream>>>(hb, w_rqkv + (size_t)i*QZ, nullptr, nullptr, q, k, v, 256, 768);
        attn_kernel<<<BDIM*CDIM*NHEADS, 256, 0, stream>>>(q, k, v, hb, 1);
        mgemm_kernel<1><<<gO, 256, 0, stream>>>(hb, w_ro + i*HH, nullptr, x, nullptr, nullptr, nullptr, 256, 256);

        // ---- column attention ----
        ln_kernel<<<NROWS, 256, 0, stream>>>(x, ln2_g + i*HDIM, ln2_b + i*HDIM, hb);
        mgemm_kernel<0><<<gQKV, 256, 0, stream>>>(hb, w_cqkv + (size_t)i*QZ, nullptr, nullptr, q, k, v, 256, 768);
        attn_kernel<<<BDIM*PDIM*NHEADS, 256, 0, stream>>>(q, k, v, hb, 0);
        mgemm_kernel<1><<<gO, 256, 0, stream>>>(hb, w_co + i*HH, nullptr, x, nullptr, nullptr, nullptr, 256, 256);

        // ---- FFN (2 chunks; intermediate tb aliases q region) ----
        ln_kernel<<<NROWS, 256, 0, stream>>>(x, ln3_g + i*HDIM, ln3_b + i*HDIM, hb);
        for (int ch = 0; ch < 2; ++ch) {
            mgemm_kernel<2><<<gF1, 256, 0, stream>>>(hb + (size_t)ch*HROWS*HDIM, w_f1 + (size_t)i*HF,
                                                     fb1 + i*FDIM, nullptr, tb, nullptr, nullptr, 256, 1024);
            mgemm_kernel<3><<<gF2, 256, 0, stream>>>(tb, w_f2 + (size_t)i*HF,
                                                     fb2 + i*HDIM, x + (size_t)ch*HROWS*HDIM,
                                                     nullptr, nullptr, nullptr, 1024, 256);
        }
    }

    // ---- head ----
    cvt4_kernel<<<NF/4/256, 256, 0, stream>>>(x, hb);
    for (int ch = 0; ch < 2; ++ch) {
        mgemm_kernel<2><<<gF1, 256, 0, stream>>>(hb + (size_t)ch*HROWS*HDIM, w_p1, pb1,
                                                 nullptr, tb, nullptr, nullptr, 256, 1024);
        gemv_head<<<HROWS/4, 256, 0, stream>>>(tb, pW2, pb2, y + (size_t)ch*HROWS);
    }
    final_kernel<<<BDIM*PDIM, 128, 0, stream>>>(y, uW, ub, (float*)d_out);
}

// Round 3
// 2046.194 us; speedup vs baseline: 6.7428x; 4.2094x over previous
//
#include <hip/hip_runtime.h>
#include <hip/hip_bf16.h>
#include <stdint.h>

#define NBLK   4
#define HDIM   256
#define NHEADS 8
#define RDIM   20
#define CDIM   128
#define PDIM   190
#define BDIM   2
#define FDIM   1024
#define NROWS  (BDIM*PDIM*CDIM)             // 48640
#define NF     ((size_t)NROWS*(size_t)HDIM) // 12,451,840
#define HROWS  (NROWS/2)                    // 24320

typedef __attribute__((ext_vector_type(8))) short bf16x8;
typedef __attribute__((ext_vector_type(4))) float f32x4;

__device__ __forceinline__ short f2b(float f){
    uint32_t u = __float_as_uint(f);
    u += 0x7fff + ((u >> 16) & 1);          // RNE
    return (short)(u >> 16);
}
__device__ __forceinline__ float b2f(short s){
    return __uint_as_float(((uint32_t)(uint16_t)s) << 16);
}
__device__ __forceinline__ float gelu_tanh(float x){
    const float k0 = 0.7978845608028654f;
    const float k1 = 0.044715f;
    return 0.5f*x*(1.0f + tanhf(k0*(x + k1*x*x*x)));
}
__device__ __forceinline__ void async16(const void* g, void* l){
    __builtin_amdgcn_global_load_lds(
        (const __attribute__((address_space(1))) void*)g,
        (__attribute__((address_space(3))) void*)l, 16, 0, 0);
}

// ---------------------------------------------------------------------------
// Embedding + pairwise row-sum (fp32 residual init)
// ---------------------------------------------------------------------------
__global__ __launch_bounds__(256) void embed_kernel(
    const int* __restrict__ tokens, const float* __restrict__ emb,
    float* __restrict__ x)
{
    int n = blockIdx.x;
    int h = threadIdx.x;
    int c  = n % CDIM;
    int bp = n / CDIM;
    int p  = bp % PDIM;
    int b  = bp / PDIM;
    int i = 0, rem = p;
    while (rem >= (RDIM - 1 - i)) { rem -= (RDIM - 1 - i); ++i; }
    int j = i + 1 + rem;
    int t1 = tokens[(b*RDIM + i)*CDIM + c];
    int t2 = tokens[(b*RDIM + j)*CDIM + c];
    x[(size_t)n*HDIM + h] = emb[t1*HDIM + h] + emb[t2*HDIM + h];
}

// ---------------------------------------------------------------------------
// LayerNorm fp32 -> bf16
// ---------------------------------------------------------------------------
__global__ __launch_bounds__(256) void ln_kernel(
    const float* __restrict__ X, const float* __restrict__ g,
    const float* __restrict__ bta, short* __restrict__ Out)
{
    int n = blockIdx.x;
    int h = threadIdx.x;
    float v = X[(size_t)n*HDIM + h];
    float s1 = v, s2 = v*v;
    #pragma unroll
    for (int off = 1; off < 64; off <<= 1) {
        s1 += __shfl_xor(s1, off);
        s2 += __shfl_xor(s2, off);
    }
    __shared__ float red[2][4];
    int wave = h >> 6;
    if ((h & 63) == 0) { red[0][wave] = s1; red[1][wave] = s2; }
    __syncthreads();
    s1 = red[0][0] + red[0][1] + red[0][2] + red[0][3];
    s2 = red[1][0] + red[1][1] + red[1][2] + red[1][3];
    float mu  = s1 * (1.0f/HDIM);
    float var = s2 * (1.0f/HDIM) - mu*mu;
    float inv = rsqrtf(var + 1e-5f);
    Out[(size_t)n*HDIM + h] = f2b((v - mu)*inv*g[h] + bta[h]);
}

__global__ __launch_bounds__(256) void cvt4_kernel(
    const float* __restrict__ in, short* __restrict__ out)
{
    size_t i = (size_t)blockIdx.x*256 + threadIdx.x;
    float4 f = ((const float4*)in)[i];
    short4 s;
    s.x = f2b(f.x); s.y = f2b(f.y); s.z = f2b(f.z); s.w = f2b(f.w);
    ((short4*)out)[i] = s;
}

// ---------------------------------------------------------------------------
// Weight transpose+convert: in f32 [K][M] -> out bf16 [M][K]
// ---------------------------------------------------------------------------
__global__ __launch_bounds__(256) void tconv_kernel(
    const float* __restrict__ in, short* __restrict__ out,
    int K, int M, size_t inz, size_t outz)
{
    __shared__ float t[32][33];
    in  += (size_t)blockIdx.z * inz;
    out += (size_t)blockIdx.z * outz;
    int m0 = blockIdx.x*32, k0 = blockIdx.y*32;
    int r = threadIdx.x >> 5, c = threadIdx.x & 31;
    #pragma unroll
    for (int i = 0; i < 4; ++i)
        t[r + i*8][c] = in[(size_t)(k0 + r + i*8)*M + m0 + c];
    __syncthreads();
    #pragma unroll
    for (int i = 0; i < 4; ++i) {
        int rr = r + i*8;
        out[(size_t)(m0 + rr)*K + k0 + c] = f2b(t[c][rr]);
    }
}

// ---------------------------------------------------------------------------
// bf16 MFMA GEMM (m97 structure): Out = A[rows,K] @ Wt[M,K]^T
// ---------------------------------------------------------------------------
template<int EPI>
__global__ __launch_bounds__(256) void mgemm_kernel(
    const short* __restrict__ A, const short* __restrict__ Wt,
    const float* __restrict__ bias,
    float* __restrict__ OutF,
    short* __restrict__ OB0, short* __restrict__ OB1, short* __restrict__ OB2,
    int K, int M)
{
    __shared__ short As[128*32];
    __shared__ short Bs[128*32];
    const int tid  = threadIdx.x;
    const int lane = tid & 63, wid = tid >> 6;
    const int wr = wid >> 1, wc = wid & 1;
    const int row0 = blockIdx.y * 128, col0 = blockIdx.x * 128;

    f32x4 acc[4][4] = {};

    const int b_lo = wid*1024 + lane*16;

    for (int k0 = 0; k0 < K; k0 += 32) {
        __syncthreads();
        #pragma unroll
        for (int it = 0; it < 2; ++it) {
            int b  = b_lo + it*4096;
            int r  = b >> 6;
            int cb = b & 63;
            const char* ga = (const char*)A  + ((size_t)(row0 + r)*K + k0)*2 + cb;
            const char* gb = (const char*)Wt + ((size_t)(col0 + r)*K + k0)*2 + cb;
            async16(ga, (char*)As + (size_t)(wid*1024 + it*4096));
            async16(gb, (char*)Bs + (size_t)(wid*1024 + it*4096));
        }
        __syncthreads();

        bf16x8 af[4], bfr[4];
        #pragma unroll
        for (int m = 0; m < 4; ++m)
            af[m] = *(const bf16x8*)(As + ((wr*64 + m*16 + (lane & 15))*32 + (lane >> 4)*8));
        #pragma unroll
        for (int n = 0; n < 4; ++n)
            bfr[n] = *(const bf16x8*)(Bs + ((wc*64 + n*16 + (lane & 15))*32 + (lane >> 4)*8));
        #pragma unroll
        for (int m = 0; m < 4; ++m)
            #pragma unroll
            for (int n = 0; n < 4; ++n)
                acc[m][n] = __builtin_amdgcn_mfma_f32_16x16x32_bf16(af[m], bfr[n], acc[m][n], 0, 0, 0);
    }

    const int rb  = row0 + wr*64 + ((lane >> 4) << 2);
    const int cb0 = col0 + wc*64 + (lane & 15);
    #pragma unroll
    for (int m = 0; m < 4; ++m) {
        #pragma unroll
        for (int n = 0; n < 4; ++n) {
            int col = cb0 + n*16;
            #pragma unroll
            for (int r = 0; r < 4; ++r) {
                int row = rb + m*16 + r;
                float vv = acc[m][n][r];
                if (EPI == 0) {
                    int sec = col >> 8, cc = col & 255;
                    short* o = (sec == 0) ? OB0 : ((sec == 1) ? OB1 : OB2);
                    o[(size_t)row*HDIM + cc] = f2b(vv);
                } else if (EPI == 1) {
                    OutF[(size_t)row*HDIM + col] += vv;
                } else if (EPI == 2) {
                    OB0[(size_t)row*M + col] = f2b(gelu_tanh(vv + bias[col]));
                } else {
                    OutF[(size_t)row*HDIM + col] += vv + bias[col];
                }
            }
        }
    }
}

// ---------------------------------------------------------------------------
// MFMA attention. One block per (b, other, head); 4 waves; LP = padded L.
// K staged [LP][32] bf16 (linear, async16); V staged transposed Vt[32][LP]
// with row-XOR swizzle; P per-wave [16][LP] with row-XOR swizzle.
// Frag layouts (verified, guide §3): A row=l&15,k=(l>>4)*8+j; B col=l&15,
// k=(l>>4)*8+j; C/D row=(l>>4)*4+reg, col=l&15.
// ---------------------------------------------------------------------------
template<int LP>
__global__ __launch_bounds__(256) void attn_mfma(
    const short* __restrict__ Q, const short* __restrict__ K,
    const short* __restrict__ V, short* __restrict__ O,
    int Lreal, int isRow)
{
    constexpr int NT  = LP/16;     // key tiles
    constexpr int NKT = LP/32;     // PV K-steps
    constexpr int NCH = LP/64;     // q-chunks per wave
    constexpr int LPB = LP*2;      // LDS row bytes (128B-aligned: 384 or 256)

    __shared__ short Ks[LP*32];
    __shared__ short Vt[32*LP];
    __shared__ short Ps[4*16*LP];

    const int bid  = blockIdx.x;
    const int head = bid & 7;
    size_t base; int S;
    if (isRow) {
        int c = (bid >> 3) & (CDIM-1);
        int b = bid >> 10;
        base = ((size_t)b*PDIM*CDIM + c)*HDIM + head*32;
        S = CDIM*HDIM;
    } else {
        int p = (bid >> 3) % PDIM;
        int b = bid / (8*PDIM);
        base = ((size_t)(b*PDIM + p)*CDIM)*HDIM + head*32;
        S = HDIM;
    }

    const int tid  = threadIdx.x;
    const int lane = tid & 63, wid = tid >> 6;
    const int lq = lane & 15, lk = lane >> 4;

    // ---- stage K [LP][32] linear via global_load_lds (dst = uniform + lane*16)
    #pragma unroll
    for (int it = 0; it < LP/64; ++it) {
        int t16 = it*256 + tid;            // 16B unit
        int row = t16 >> 2;
        int rc  = row < Lreal ? row : Lreal-1;
        async16((const char*)K + (base + (size_t)rc*S + (t16 & 3)*8)*2,
                (char*)Ks + (size_t)t16*16);
    }
    // ---- stage V transposed with XOR swizzle: Vt[d][key], byte ^= (d&7)<<4
    #pragma unroll
    for (int it = 0; it < LP/32; ++it) {
        int e   = it*256 + tid;            // 4-elem group
        int row = e >> 3;                  // key
        int d4  = (e & 7)*4;
        int rc  = row < Lreal ? row : Lreal-1;
        short4 v4 = *(const short4*)(V + base + (size_t)rc*S + d4);
        #pragma unroll
        for (int j = 0; j < 4; ++j) {
            int d = d4 + j;
            int off = ((d*LP + row)*2) ^ ((d & 7) << 4);
            *(short*)((char*)Vt + off) = ((const short*)&v4)[j];
        }
    }
    __syncthreads();   // drains vmcnt (async16) + lgkmcnt

    const float scale = 0.17677669529663687f; // 1/sqrt(32)
    char* pbase = (char*)Ps + wid*(16*LPB);
    const f32x4 zero = {0.f, 0.f, 0.f, 0.f};

    #pragma unroll 1
    for (int cc = 0; cc < NCH; ++cc) {
        const int chunk = wid + cc*4;
        const int qrow0 = chunk*16;

        // Q A-frag straight from global (row clamped)
        int qr = qrow0 + lq; if (qr >= Lreal) qr = Lreal-1;
        bf16x8 qa = *(const bf16x8*)(Q + base + (size_t)qr*S + lk*8);

        // S tiles
        f32x4 s[NT];
        #pragma unroll
        for (int t = 0; t < NT; ++t) {
            bf16x8 kb = *(const bf16x8*)(Ks + (t*16 + lq)*32 + lk*8);
            s[t] = __builtin_amdgcn_mfma_f32_16x16x32_bf16(qa, kb, zero, 0, 0, 0);
        }
        // mask invalid key columns (only possible in last tile)
        if ((NT-1)*16 + lq >= Lreal) {
            #pragma unroll
            for (int r = 0; r < 4; ++r) s[NT-1][r] = -1e30f;
        }
        // row max (reduce across the 16-lane col group)
        float mx[4] = {-1e30f, -1e30f, -1e30f, -1e30f};
        #pragma unroll
        for (int t = 0; t < NT; ++t)
            #pragma unroll
            for (int r = 0; r < 4; ++r) mx[r] = fmaxf(mx[r], s[t][r]);
        #pragma unroll
        for (int off = 1; off < 16; off <<= 1)
            #pragma unroll
            for (int r = 0; r < 4; ++r) mx[r] = fmaxf(mx[r], __shfl_xor(mx[r], off));
        // exp + row sum (normalization deferred to store)
        float sm[4] = {0.f, 0.f, 0.f, 0.f};
        #pragma unroll
        for (int t = 0; t < NT; ++t)
            #pragma unroll
            for (int r = 0; r < 4; ++r) {
                float p = __expf((s[t][r] - mx[r])*scale);
                s[t][r] = p; sm[r] += p;
            }
        #pragma unroll
        for (int off = 1; off < 16; off <<= 1)
            #pragma unroll
            for (int r = 0; r < 4; ++r) sm[r] += __shfl_xor(sm[r], off);

        // P -> per-wave LDS (bf16, row-XOR swizzle)
        #pragma unroll
        for (int t = 0; t < NT; ++t)
            #pragma unroll
            for (int r = 0; r < 4; ++r) {
                int row = lk*4 + r, col = t*16 + lq;
                int off = (row*LPB + col*2) ^ ((row & 7) << 4);
                *(short*)(pbase + off) = f2b(s[t][r]);
            }
        asm volatile("s_waitcnt lgkmcnt(0)" ::: "memory");
        __builtin_amdgcn_sched_barrier(0);

        // PV: O[16][32] = P[16][LP] @ V[LP][32]
        f32x4 acc0 = zero, acc1 = zero;
        #pragma unroll
        for (int kt = 0; kt < NKT; ++kt) {
            bf16x8 pa = *(const bf16x8*)(pbase + ((lq*LPB + kt*64 + lk*16) ^ ((lq & 7) << 4)));
            bf16x8 v0 = *(const bf16x8*)((char*)Vt + ((lq*LPB      + kt*64 + lk*16) ^ ((lq & 7) << 4)));
            bf16x8 v1 = *(const bf16x8*)((char*)Vt + (((16+lq)*LPB + kt*64 + lk*16) ^ ((lq & 7) << 4)));
            acc0 = __builtin_amdgcn_mfma_f32_16x16x32_bf16(pa, v0, acc0, 0, 0, 0);
            acc1 = __builtin_amdgcn_mfma_f32_16x16x32_bf16(pa, v1, acc1, 0, 0, 0);
        }
        __builtin_amdgcn_sched_barrier(0);  // keep next chunk's P writes behind these reads

        // store (deferred 1/sum)
        #pragma unroll
        for (int r = 0; r < 4; ++r) {
            int row = qrow0 + lk*4 + r;
            if (row < Lreal) {
                float inv = 1.0f / sm[r];
                O[base + (size_t)row*S + lq]      = f2b(acc0[r]*inv);
                O[base + (size_t)row*S + 16 + lq] = f2b(acc1[r]*inv);
            }
        }
    }
}

// ---------------------------------------------------------------------------
__global__ __launch_bounds__(256) void gemv_head(
    const short* __restrict__ T, const float* __restrict__ w,
    const float* __restrict__ bias, float* __restrict__ y)
{
    int row  = blockIdx.x*4 + (threadIdx.x >> 6);
    int lane = threadIdx.x & 63;
    const short* t = T + (size_t)row*FDIM;
    float acc = 0.f;
    #pragma unroll
    for (int it = 0; it < 4; ++it) {
        int ci = it*64 + lane;
        short4 tv = *(const short4*)(t + ci*4);
        float4 wv = *(const float4*)(w + ci*4);
        acc += b2f(tv.x)*wv.x + b2f(tv.y)*wv.y + b2f(tv.z)*wv.z + b2f(tv.w)*wv.w;
    }
    #pragma unroll
    for (int off = 1; off < 64; off <<= 1) acc += __shfl_xor(acc, off);
    if (lane == 0) y[row] = acc + bias[0];
}

__global__ __launch_bounds__(128) void final_kernel(
    const float* __restrict__ y, const float* __restrict__ uW,
    const float* __restrict__ ub, float* __restrict__ out)
{
    int bp = blockIdx.x;
    int c  = threadIdx.x;
    float v = y[(size_t)bp*CDIM + c]*uW[c];
    #pragma unroll
    for (int off = 1; off < 64; off <<= 1) v += __shfl_xor(v, off);
    __shared__ float r[2];
    if ((c & 63) == 0) r[c >> 6] = v;
    __syncthreads();
    if (c == 0) out[bp] = r[0] + r[1] + ub[0];
}

// ---------------------------------------------------------------------------
extern "C" void kernel_launch(void* const* d_in, const int* in_sizes, int n_in,
                              void* d_out, int out_size, void* d_ws, size_t ws_size,
                              hipStream_t stream)
{
    const int*   tokens = (const int*)  d_in[0];
    const float* emb    = (const float*)d_in[1];
    const float* ln1_g  = (const float*)d_in[2];
    const float* ln1_b  = (const float*)d_in[3];
    const float* rWq    = (const float*)d_in[4];
    const float* rWk    = (const float*)d_in[5];
    const float* rWv    = (const float*)d_in[6];
    const float* rWo    = (const float*)d_in[7];
    const float* ln2_g  = (const float*)d_in[8];
    const float* ln2_b  = (const float*)d_in[9];
    const float* cWq    = (const float*)d_in[10];
    const float* cWk    = (const float*)d_in[11];
    const float* cWv    = (const float*)d_in[12];
    const float* cWo    = (const float*)d_in[13];
    const float* ln3_g  = (const float*)d_in[14];
    const float* ln3_b  = (const float*)d_in[15];
    const float* fW1    = (const float*)d_in[16];
    const float* fb1    = (const float*)d_in[17];
    const float* fW2    = (const float*)d_in[18];
    const float* fb2    = (const float*)d_in[19];
    const float* pW1    = (const float*)d_in[20];
    const float* pb1    = (const float*)d_in[21];
    const float* pW2    = (const float*)d_in[22];
    const float* pb2    = (const float*)d_in[23];
    const float* uW     = (const float*)d_in[24];
    const float* ub     = (const float*)d_in[25];

    float* x  = (float*)d_ws;
    short* q  = (short*)(x + NF);
    short* k  = q + NF;
    short* v  = k + NF;
    short* hb = v + NF;
    float* y  = (float*)(hb + NF);
    short* wts = (short*)(y + NROWS);
    short* w_rqkv = wts;
    short* w_cqkv = w_rqkv + 4*768*256;
    short* w_ro   = w_cqkv + 4*768*256;
    short* w_co   = w_ro   + 4*256*256;
    short* w_f1   = w_co   + 4*256*256;
    short* w_f2   = w_f1   + (size_t)4*1024*256;
    short* w_p1   = w_f2   + (size_t)4*1024*256;
    short* tb = q;

    const size_t HH = 65536, HF = 262144, QZ = 768*256;

    tconv_kernel<<<dim3(8,8,NBLK),   256, 0, stream>>>(rWq, w_rqkv,          256, 256,  HH, QZ);
    tconv_kernel<<<dim3(8,8,NBLK),   256, 0, stream>>>(rWk, w_rqkv + 65536,  256, 256,  HH, QZ);
    tconv_kernel<<<dim3(8,8,NBLK),   256, 0, stream>>>(rWv, w_rqkv + 131072, 256, 256,  HH, QZ);
    tconv_kernel<<<dim3(8,8,NBLK),   256, 0, stream>>>(rWo, w_ro,            256, 256,  HH, HH);
    tconv_kernel<<<dim3(8,8,NBLK),   256, 0, stream>>>(cWq, w_cqkv,          256, 256,  HH, QZ);
    tconv_kernel<<<dim3(8,8,NBLK),   256, 0, stream>>>(cWk, w_cqkv + 65536,  256, 256,  HH, QZ);
    tconv_kernel<<<dim3(8,8,NBLK),   256, 0, stream>>>(cWv, w_cqkv + 131072, 256, 256,  HH, QZ);
    tconv_kernel<<<dim3(8,8,NBLK),   256, 0, stream>>>(cWo, w_co,            256, 256,  HH, HH);
    tconv_kernel<<<dim3(32,8,NBLK),  256, 0, stream>>>(fW1, w_f1,            256, 1024, HF, HF);
    tconv_kernel<<<dim3(8,32,NBLK),  256, 0, stream>>>(fW2, w_f2,            1024, 256, HF, HF);
    tconv_kernel<<<dim3(32,8,1),     256, 0, stream>>>(pW1, w_p1,            256, 1024, HF, HF);

    embed_kernel<<<NROWS, 256, 0, stream>>>(tokens, emb, x);

    const dim3 gQKV(6, NROWS/128);
    const dim3 gO(2, NROWS/128);
    const dim3 gF1(8, HROWS/128);
    const dim3 gF2(2, HROWS/128);

    for (int i = 0; i < NBLK; ++i) {
        // ---- row attention (pair axis, L=190 padded to 192) ----
        ln_kernel<<<NROWS, 256, 0, stream>>>(x, ln1_g + i*HDIM, ln1_b + i*HDIM, hb);
        mgemm_kernel<0><<<gQKV, 256, 0, stream>>>(hb, w_rqkv + (size_t)i*QZ, nullptr, nullptr, q, k, v, 256, 768);
        attn_mfma<192><<<BDIM*CDIM*NHEADS, 256, 0, stream>>>(q, k, v, hb, PDIM, 1);
        mgemm_kernel<1><<<gO, 256, 0, stream>>>(hb, w_ro + i*HH, nullptr, x, nullptr, nullptr, nullptr, 256, 256);

        // ---- column attention (L=128) ----
        ln_kernel<<<NROWS, 256, 0, stream>>>(x, ln2_g + i*HDIM, ln2_b + i*HDIM, hb);
        mgemm_kernel<0><<<gQKV, 256, 0, stream>>>(hb, w_cqkv + (size_t)i*QZ, nullptr, nullptr, q, k, v, 256, 768);
        attn_mfma<128><<<BDIM*PDIM*NHEADS, 256, 0, stream>>>(q, k, v, hb, CDIM, 0);
        mgemm_kernel<1><<<gO, 256, 0, stream>>>(hb, w_co + i*HH, nullptr, x, nullptr, nullptr, nullptr, 256, 256);

        // ---- FFN ----
        ln_kernel<<<NROWS, 256, 0, stream>>>(x, ln3_g + i*HDIM, ln3_b + i*HDIM, hb);
        for (int ch = 0; ch < 2; ++ch) {
            mgemm_kernel<2><<<gF1, 256, 0, stream>>>(hb + (size_t)ch*HROWS*HDIM, w_f1 + (size_t)i*HF,
                                                     fb1 + i*FDIM, nullptr, tb, nullptr, nullptr, 256, 1024);
            mgemm_kernel<3><<<gF2, 256, 0, stream>>>(tb, w_f2 + (size_t)i*HF,
                                                     fb2 + i*HDIM, x + (size_t)ch*HROWS*HDIM,
                                                     nullptr, nullptr, nullptr, 1024, 256);
        }
    }

    // ---- head ----
    cvt4_kernel<<<NF/4/256, 256, 0, stream>>>(x, hb);
    for (int ch = 0; ch < 2; ++ch) {
        mgemm_kernel<2><<<gF1, 256, 0, stream>>>(hb + (size_t)ch*HROWS*HDIM, w_p1, pb1,
                                                 nullptr, tb, nullptr, nullptr, 256, 1024);
        gemv_head<<<HROWS/4, 256, 0, stream>>>(tb, pW2, pb2, y + (size_t)ch*HROWS);
    }
    final_kernel<<<BDIM*PDIM, 128, 0, stream>>>(y, uW, ub, (float*)d_out);
}

// Round 5
// 1786.690 us; speedup vs baseline: 7.7221x; 1.1452x over previous
//
#include <hip/hip_runtime.h>
#include <hip/hip_bf16.h>
#include <stdint.h>

#define NBLK   4
#define HDIM   256
#define NHEADS 8
#define RDIM   20
#define CDIM   128
#define PDIM   190
#define BDIM   2
#define FDIM   1024
#define NROWS  (BDIM*PDIM*CDIM)             // 48640
#define NF     ((size_t)NROWS*(size_t)HDIM) // 12,451,840
#define HROWS  (NROWS/2)                    // 24320

typedef __attribute__((ext_vector_type(8))) short bf16x8;
typedef __attribute__((ext_vector_type(4))) float f32x4;

__device__ __forceinline__ short f2b(float f){
    uint32_t u = __float_as_uint(f);
    u += 0x7fff + ((u >> 16) & 1);          // RNE
    return (short)(u >> 16);
}
__device__ __forceinline__ float b2f(short s){
    return __uint_as_float(((uint32_t)(uint16_t)s) << 16);
}
__device__ __forceinline__ float gelu_tanh(float x){
    const float k0 = 0.7978845608028654f;
    const float k1 = 0.044715f;
    return 0.5f*x*(1.0f + tanhf(k0*(x + k1*x*x*x)));
}
__device__ __forceinline__ void async16(const void* g, void* l){
    __builtin_amdgcn_global_load_lds(
        (const __attribute__((address_space(1))) void*)g,
        (__attribute__((address_space(3))) void*)l, 16, 0, 0);
}

// ---------------------------------------------------------------------------
// Embedding + pairwise row-sum (fp32 residual init). One wave per (b,p,c) row.
// ---------------------------------------------------------------------------
__global__ __launch_bounds__(256) void embed_kernel(
    const int* __restrict__ tokens, const float* __restrict__ emb,
    float* __restrict__ x)
{
    int n    = blockIdx.x*4 + (threadIdx.x >> 6);
    int lane = threadIdx.x & 63;
    int c  = n % CDIM;
    int bp = n / CDIM;
    int p  = bp % PDIM;
    int b  = bp / PDIM;
    int i = 0, rem = p;
    while (rem >= (RDIM - 1 - i)) { rem -= (RDIM - 1 - i); ++i; }
    int j = i + 1 + rem;
    int t1 = tokens[(b*RDIM + i)*CDIM + c];
    int t2 = tokens[(b*RDIM + j)*CDIM + c];
    float4 e1 = *(const float4*)(emb + (size_t)t1*HDIM + lane*4);
    float4 e2 = *(const float4*)(emb + (size_t)t2*HDIM + lane*4);
    float4 o; o.x = e1.x+e2.x; o.y = e1.y+e2.y; o.z = e1.z+e2.z; o.w = e1.w+e2.w;
    *(float4*)(x + (size_t)n*HDIM + lane*4) = o;
}

// ---------------------------------------------------------------------------
// LayerNorm fp32 -> bf16. One wave per row, float4 per lane.
// ---------------------------------------------------------------------------
__global__ __launch_bounds__(256) void ln_kernel(
    const float* __restrict__ X, const float* __restrict__ g,
    const float* __restrict__ bta, short* __restrict__ Out)
{
    int row  = blockIdx.x*4 + (threadIdx.x >> 6);
    int lane = threadIdx.x & 63;
    float4 v = *(const float4*)(X + (size_t)row*HDIM + lane*4);
    float s1 = v.x + v.y + v.z + v.w;
    float s2 = v.x*v.x + v.y*v.y + v.z*v.z + v.w*v.w;
    #pragma unroll
    for (int off = 1; off < 64; off <<= 1) {
        s1 += __shfl_xor(s1, off);
        s2 += __shfl_xor(s2, off);
    }
    float mu  = s1 * (1.0f/HDIM);
    float var = s2 * (1.0f/HDIM) - mu*mu;
    float inv = rsqrtf(var + 1e-5f);
    float4 gg = *(const float4*)(g   + lane*4);
    float4 bb = *(const float4*)(bta + lane*4);
    short4 o;
    o.x = f2b((v.x - mu)*inv*gg.x + bb.x);
    o.y = f2b((v.y - mu)*inv*gg.y + bb.y);
    o.z = f2b((v.z - mu)*inv*gg.z + bb.z);
    o.w = f2b((v.w - mu)*inv*gg.w + bb.w);
    *(short4*)(Out + (size_t)row*HDIM + lane*4) = o;
}

__global__ __launch_bounds__(256) void cvt4_kernel(
    const float* __restrict__ in, short* __restrict__ out)
{
    size_t i = (size_t)blockIdx.x*256 + threadIdx.x;
    float4 f = ((const float4*)in)[i];
    short4 s;
    s.x = f2b(f.x); s.y = f2b(f.y); s.z = f2b(f.z); s.w = f2b(f.w);
    ((short4*)out)[i] = s;
}

// ---------------------------------------------------------------------------
// Weight transpose+convert: in f32 [K][M] -> out bf16 [M][K]
// ---------------------------------------------------------------------------
__global__ __launch_bounds__(256) void tconv_kernel(
    const float* __restrict__ in, short* __restrict__ out,
    int K, int M, size_t inz, size_t outz)
{
    __shared__ float t[32][33];
    in  += (size_t)blockIdx.z * inz;
    out += (size_t)blockIdx.z * outz;
    int m0 = blockIdx.x*32, k0 = blockIdx.y*32;
    int r = threadIdx.x >> 5, c = threadIdx.x & 31;
    #pragma unroll
    for (int i = 0; i < 4; ++i)
        t[r + i*8][c] = in[(size_t)(k0 + r + i*8)*M + m0 + c];
    __syncthreads();
    #pragma unroll
    for (int i = 0; i < 4; ++i) {
        int rr = r + i*8;
        out[(size_t)(m0 + rr)*K + k0 + c] = f2b(t[c][rr]);
    }
}

// ---------------------------------------------------------------------------
// bf16 MFMA GEMM, 1-deep prefetch pipeline: Out = A[rows,K] @ Wt[M,K]^T
// 128x128 tile, BK=32, double-buffered LDS; staging source-swizzled
// (c16 ^= row&3 on 16B units) so frag ds_read_b128 is ~conflict-free.
// EPI 0: QKV split store bf16; 1: OutF += acc; 2: bf16(gelu(acc+bias));
// 3: OutF += acc + bias
// ---------------------------------------------------------------------------
template<int EPI>
__global__ __launch_bounds__(256) void mgemm_kernel(
    const short* __restrict__ A, const short* __restrict__ Wt,
    const float* __restrict__ bias,
    float* __restrict__ OutF,
    short* __restrict__ OB0, short* __restrict__ OB1, short* __restrict__ OB2,
    int K, int M)
{
    __shared__ short As[2][128*32];
    __shared__ short Bs[2][128*32];
    const int tid  = threadIdx.x;
    const int lane = tid & 63, wid = tid >> 6;
    const int lq = lane & 15, lk = lane >> 4;
    const int wr = wid >> 1, wc = wid & 1;
    const int row0 = blockIdx.y * 128, col0 = blockIdx.x * 128;

    f32x4 acc[4][4] = {};

    auto stage = [&](int buf, int k0) {
        #pragma unroll
        for (int u = 0; u < 2; ++u) {
            int b   = wid*1024 + lane*16 + u*4096;   // dest byte in 8KB tile
            int r   = b >> 6;                        // tile row (64B rows)
            int c16 = (b >> 4) & 3;                  // 16B slot in row
            int cs  = (c16 ^ (r & 3)) * 8;           // swizzled source col (shorts)
            async16(A  + (size_t)(row0 + r)*K + k0 + cs, (char*)As[buf] + b);
            async16(Wt + (size_t)(col0 + r)*K + k0 + cs, (char*)Bs[buf] + b);
        }
    };

    stage(0, 0);
    const int NTK = K >> 5;
    for (int t = 0; t < NTK; ++t) {
        const int cur = t & 1;
        asm volatile("s_waitcnt vmcnt(0)" ::: "memory");
        __builtin_amdgcn_s_barrier();
        __builtin_amdgcn_sched_barrier(0);
        if (t + 1 < NTK) stage(cur ^ 1, (t + 1)*32);

        bf16x8 af[4], bfr[4];
        #pragma unroll
        for (int m = 0; m < 4; ++m) {
            int row = wr*64 + m*16 + lq;
            af[m] = *(const bf16x8*)((const char*)As[cur] + row*64 + ((lk ^ (lq & 3)) << 4));
        }
        #pragma unroll
        for (int n = 0; n < 4; ++n) {
            int row = wc*64 + n*16 + lq;
            bfr[n] = *(const bf16x8*)((const char*)Bs[cur] + row*64 + ((lk ^ (lq & 3)) << 4));
        }
        #pragma unroll
        for (int m = 0; m < 4; ++m)
            #pragma unroll
            for (int n = 0; n < 4; ++n)
                acc[m][n] = __builtin_amdgcn_mfma_f32_16x16x32_bf16(af[m], bfr[n], acc[m][n], 0, 0, 0);
    }

    // D layout: row = (lane>>4)*4 + reg, col = lane&15
    const int rb  = row0 + wr*64 + (lk << 2);
    const int cb0 = col0 + wc*64 + lq;
    #pragma unroll
    for (int m = 0; m < 4; ++m) {
        #pragma unroll
        for (int n = 0; n < 4; ++n) {
            int col = cb0 + n*16;
            #pragma unroll
            for (int r = 0; r < 4; ++r) {
                int row = rb + m*16 + r;
                float vv = acc[m][n][r];
                if (EPI == 0) {
                    int sec = col >> 8, cc = col & 255;
                    short* o = (sec == 0) ? OB0 : ((sec == 1) ? OB1 : OB2);
                    o[(size_t)row*HDIM + cc] = f2b(vv);
                } else if (EPI == 1) {
                    OutF[(size_t)row*HDIM + col] += vv;
                } else if (EPI == 2) {
                    OB0[(size_t)row*M + col] = f2b(gelu_tanh(vv + bias[col]));
                } else {
                    OutF[(size_t)row*HDIM + col] += vv + bias[col];
                }
            }
        }
    }
}

// ---------------------------------------------------------------------------
// MFMA attention (round-3 verbatim, known-good). One block per (b,other,head).
// K staged [LP][32] bf16 (linear, async16); V staged transposed Vt[32][LP]
// with row-XOR swizzle; P per-wave [16][LP] with row-XOR swizzle.
// ---------------------------------------------------------------------------
template<int LP>
__global__ __launch_bounds__(256) void attn_mfma(
    const short* __restrict__ Q, const short* __restrict__ K,
    const short* __restrict__ V, short* __restrict__ O,
    int Lreal, int isRow)
{
    constexpr int NT  = LP/16;     // key tiles
    constexpr int NKT = LP/32;     // PV K-steps
    constexpr int NCH = LP/64;     // q-chunks per wave
    constexpr int LPB = LP*2;      // LDS row bytes

    __shared__ short Ks[LP*32];
    __shared__ short Vt[32*LP];
    __shared__ short Ps[4*16*LP];

    const int bid  = blockIdx.x;
    const int head = bid & 7;
    size_t base; int S;
    if (isRow) {
        int c = (bid >> 3) & (CDIM-1);
        int b = bid >> 10;
        base = ((size_t)b*PDIM*CDIM + c)*HDIM + head*32;
        S = CDIM*HDIM;
    } else {
        int p = (bid >> 3) % PDIM;
        int b = bid / (8*PDIM);
        base = ((size_t)(b*PDIM + p)*CDIM)*HDIM + head*32;
        S = HDIM;
    }

    const int tid  = threadIdx.x;
    const int lane = tid & 63, wid = tid >> 6;
    const int lq = lane & 15, lk = lane >> 4;

    // ---- stage K [LP][32] linear via global_load_lds
    #pragma unroll
    for (int it = 0; it < LP/64; ++it) {
        int t16 = it*256 + tid;            // 16B unit
        int row = t16 >> 2;
        int rc  = row < Lreal ? row : Lreal-1;
        async16((const char*)K + (base + (size_t)rc*S + (t16 & 3)*8)*2,
                (char*)Ks + (size_t)t16*16);
    }
    // ---- stage V transposed with XOR swizzle: Vt[d][key], byte ^= (d&7)<<4
    #pragma unroll
    for (int it = 0; it < LP/32; ++it) {
        int e   = it*256 + tid;            // 4-elem group
        int row = e >> 3;                  // key
        int d4  = (e & 7)*4;
        int rc  = row < Lreal ? row : Lreal-1;
        short4 v4 = *(const short4*)(V + base + (size_t)rc*S + d4);
        #pragma unroll
        for (int j = 0; j < 4; ++j) {
            int d = d4 + j;
            int off = ((d*LP + row)*2) ^ ((d & 7) << 4);
            *(short*)((char*)Vt + off) = ((const short*)&v4)[j];
        }
    }
    __syncthreads();   // drains vmcnt (async16) + lgkmcnt

    const float scale = 0.17677669529663687f; // 1/sqrt(32)
    char* pbase = (char*)Ps + wid*(16*LPB);
    const f32x4 zero = {0.f, 0.f, 0.f, 0.f};

    #pragma unroll 1
    for (int cc = 0; cc < NCH; ++cc) {
        const int chunk = wid + cc*4;
        const int qrow0 = chunk*16;

        int qr = qrow0 + lq; if (qr >= Lreal) qr = Lreal-1;
        bf16x8 qa = *(const bf16x8*)(Q + base + (size_t)qr*S + lk*8);

        f32x4 s[NT];
        #pragma unroll
        for (int t = 0; t < NT; ++t) {
            bf16x8 kb = *(const bf16x8*)(Ks + (t*16 + lq)*32 + lk*8);
            s[t] = __builtin_amdgcn_mfma_f32_16x16x32_bf16(qa, kb, zero, 0, 0, 0);
        }
        if ((NT-1)*16 + lq >= Lreal) {
            #pragma unroll
            for (int r = 0; r < 4; ++r) s[NT-1][r] = -1e30f;
        }
        float mx[4] = {-1e30f, -1e30f, -1e30f, -1e30f};
        #pragma unroll
        for (int t = 0; t < NT; ++t)
            #pragma unroll
            for (int r = 0; r < 4; ++r) mx[r] = fmaxf(mx[r], s[t][r]);
        #pragma unroll
        for (int off = 1; off < 16; off <<= 1)
            #pragma unroll
            for (int r = 0; r < 4; ++r) mx[r] = fmaxf(mx[r], __shfl_xor(mx[r], off));
        float sm[4] = {0.f, 0.f, 0.f, 0.f};
        #pragma unroll
        for (int t = 0; t < NT; ++t)
            #pragma unroll
            for (int r = 0; r < 4; ++r) {
                float p = __expf((s[t][r] - mx[r])*scale);
                s[t][r] = p; sm[r] += p;
            }
        #pragma unroll
        for (int off = 1; off < 16; off <<= 1)
            #pragma unroll
            for (int r = 0; r < 4; ++r) sm[r] += __shfl_xor(sm[r], off);

        #pragma unroll
        for (int t = 0; t < NT; ++t)
            #pragma unroll
            for (int r = 0; r < 4; ++r) {
                int row = lk*4 + r, col = t*16 + lq;
                int off = (row*LPB + col*2) ^ ((row & 7) << 4);
                *(short*)(pbase + off) = f2b(s[t][r]);
            }
        asm volatile("s_waitcnt lgkmcnt(0)" ::: "memory");
        __builtin_amdgcn_sched_barrier(0);

        f32x4 acc0 = zero, acc1 = zero;
        #pragma unroll
        for (int kt = 0; kt < NKT; ++kt) {
            bf16x8 pa = *(const bf16x8*)(pbase + ((lq*LPB + kt*64 + lk*16) ^ ((lq & 7) << 4)));
            bf16x8 v0 = *(const bf16x8*)((char*)Vt + ((lq*LPB      + kt*64 + lk*16) ^ ((lq & 7) << 4)));
            bf16x8 v1 = *(const bf16x8*)((char*)Vt + (((16+lq)*LPB + kt*64 + lk*16) ^ ((lq & 7) << 4)));
            acc0 = __builtin_amdgcn_mfma_f32_16x16x32_bf16(pa, v0, acc0, 0, 0, 0);
            acc1 = __builtin_amdgcn_mfma_f32_16x16x32_bf16(pa, v1, acc1, 0, 0, 0);
        }
        __builtin_amdgcn_sched_barrier(0);

        #pragma unroll
        for (int r = 0; r < 4; ++r) {
            int row = qrow0 + lk*4 + r;
            if (row < Lreal) {
                float inv = 1.0f / sm[r];
                O[base + (size_t)row*S + lq]      = f2b(acc0[r]*inv);
                O[base + (size_t)row*S + 16 + lq] = f2b(acc1[r]*inv);
            }
        }
    }
}

// ---------------------------------------------------------------------------
__global__ __launch_bounds__(256) void gemv_head(
    const short* __restrict__ T, const float* __restrict__ w,
    const float* __restrict__ bias, float* __restrict__ y)
{
    int row  = blockIdx.x*4 + (threadIdx.x >> 6);
    int lane = threadIdx.x & 63;
    const short* t = T + (size_t)row*FDIM;
    float acc = 0.f;
    #pragma unroll
    for (int it = 0; it < 4; ++it) {
        int ci = it*64 + lane;
        short4 tv = *(const short4*)(t + ci*4);
        float4 wv = *(const float4*)(w + ci*4);
        acc += b2f(tv.x)*wv.x + b2f(tv.y)*wv.y + b2f(tv.z)*wv.z + b2f(tv.w)*wv.w;
    }
    #pragma unroll
    for (int off = 1; off < 64; off <<= 1) acc += __shfl_xor(acc, off);
    if (lane == 0) y[row] = acc + bias[0];
}

__global__ __launch_bounds__(128) void final_kernel(
    const float* __restrict__ y, const float* __restrict__ uW,
    const float* __restrict__ ub, float* __restrict__ out)
{
    int bp = blockIdx.x;
    int c  = threadIdx.x;
    float v = y[(size_t)bp*CDIM + c]*uW[c];
    #pragma unroll
    for (int off = 1; off < 64; off <<= 1) v += __shfl_xor(v, off);
    __shared__ float r[2];
    if ((c & 63) == 0) r[c >> 6] = v;
    __syncthreads();
    if (c == 0) out[bp] = r[0] + r[1] + ub[0];
}

// ---------------------------------------------------------------------------
extern "C" void kernel_launch(void* const* d_in, const int* in_sizes, int n_in,
                              void* d_out, int out_size, void* d_ws, size_t ws_size,
                              hipStream_t stream)
{
    const int*   tokens = (const int*)  d_in[0];
    const float* emb    = (const float*)d_in[1];
    const float* ln1_g  = (const float*)d_in[2];
    const float* ln1_b  = (const float*)d_in[3];
    const float* rWq    = (const float*)d_in[4];
    const float* rWk    = (const float*)d_in[5];
    const float* rWv    = (const float*)d_in[6];
    const float* rWo    = (const float*)d_in[7];
    const float* ln2_g  = (const float*)d_in[8];
    const float* ln2_b  = (const float*)d_in[9];
    const float* cWq    = (const float*)d_in[10];
    const float* cWk    = (const float*)d_in[11];
    const float* cWv    = (const float*)d_in[12];
    const float* cWo    = (const float*)d_in[13];
    const float* ln3_g  = (const float*)d_in[14];
    const float* ln3_b  = (const float*)d_in[15];
    const float* fW1    = (const float*)d_in[16];
    const float* fb1    = (const float*)d_in[17];
    const float* fW2    = (const float*)d_in[18];
    const float* fb2    = (const float*)d_in[19];
    const float* pW1    = (const float*)d_in[20];
    const float* pb1    = (const float*)d_in[21];
    const float* pW2    = (const float*)d_in[22];
    const float* pb2    = (const float*)d_in[23];
    const float* uW     = (const float*)d_in[24];
    const float* ub     = (const float*)d_in[25];

    float* x  = (float*)d_ws;
    short* q  = (short*)(x + NF);
    short* k  = q + NF;
    short* v  = k + NF;
    short* hb = v + NF;
    float* y  = (float*)(hb + NF);
    short* wts = (short*)(y + NROWS);
    short* w_rqkv = wts;
    short* w_cqkv = w_rqkv + 4*768*256;
    short* w_ro   = w_cqkv + 4*768*256;
    short* w_co   = w_ro   + 4*256*256;
    short* w_f1   = w_co   + 4*256*256;
    short* w_f2   = w_f1   + (size_t)4*1024*256;
    short* w_p1   = w_f2   + (size_t)4*1024*256;
    short* tb = q;

    const size_t HH = 65536, HF = 262144, QZ = 768*256;

    tconv_kernel<<<dim3(8,8,NBLK),   256, 0, stream>>>(rWq, w_rqkv,          256, 256,  HH, QZ);
    tconv_kernel<<<dim3(8,8,NBLK),   256, 0, stream>>>(rWk, w_rqkv + 65536,  256, 256,  HH, QZ);
    tconv_kernel<<<dim3(8,8,NBLK),   256, 0, stream>>>(rWv, w_rqkv + 131072, 256, 256,  HH, QZ);
    tconv_kernel<<<dim3(8,8,NBLK),   256, 0, stream>>>(rWo, w_ro,            256, 256,  HH, HH);
    tconv_kernel<<<dim3(8,8,NBLK),   256, 0, stream>>>(cWq, w_cqkv,          256, 256,  HH, QZ);
    tconv_kernel<<<dim3(8,8,NBLK),   256, 0, stream>>>(cWk, w_cqkv + 65536,  256, 256,  HH, QZ);
    tconv_kernel<<<dim3(8,8,NBLK),   256, 0, stream>>>(cWv, w_cqkv + 131072, 256, 256,  HH, QZ);
    tconv_kernel<<<dim3(8,8,NBLK),   256, 0, stream>>>(cWo, w_co,            256, 256,  HH, HH);
    tconv_kernel<<<dim3(32,8,NBLK),  256, 0, stream>>>(fW1, w_f1,            256, 1024, HF, HF);
    tconv_kernel<<<dim3(8,32,NBLK),  256, 0, stream>>>(fW2, w_f2,            1024, 256, HF, HF);
    tconv_kernel<<<dim3(32,8,1),     256, 0, stream>>>(pW1, w_p1,            256, 1024, HF, HF);

    embed_kernel<<<NROWS/4, 256, 0, stream>>>(tokens, emb, x);

    const dim3 gQKV(6, NROWS/128);
    const dim3 gO(2, NROWS/128);
    const dim3 gF1(8, HROWS/128);
    const dim3 gF2(2, HROWS/128);

    for (int i = 0; i < NBLK; ++i) {
        // ---- row attention (pair axis, L=190 padded to 192) ----
        ln_kernel<<<NROWS/4, 256, 0, stream>>>(x, ln1_g + i*HDIM, ln1_b + i*HDIM, hb);
        mgemm_kernel<0><<<gQKV, 256, 0, stream>>>(hb, w_rqkv + (size_t)i*QZ, nullptr, nullptr, q, k, v, 256, 768);
        attn_mfma<192><<<BDIM*CDIM*NHEADS, 256, 0, stream>>>(q, k, v, hb, PDIM, 1);
        mgemm_kernel<1><<<gO, 256, 0, stream>>>(hb, w_ro + i*HH, nullptr, x, nullptr, nullptr, nullptr, 256, 256);

        // ---- column attention (L=128) ----
        ln_kernel<<<NROWS/4, 256, 0, stream>>>(x, ln2_g + i*HDIM, ln2_b + i*HDIM, hb);
        mgemm_kernel<0><<<gQKV, 256, 0, stream>>>(hb, w_cqkv + (size_t)i*QZ, nullptr, nullptr, q, k, v, 256, 768);
        attn_mfma<128><<<BDIM*PDIM*NHEADS, 256, 0, stream>>>(q, k, v, hb, CDIM, 0);
        mgemm_kernel<1><<<gO, 256, 0, stream>>>(hb, w_co + i*HH, nullptr, x, nullptr, nullptr, nullptr, 256, 256);

        // ---- FFN ----
        ln_kernel<<<NROWS/4, 256, 0, stream>>>(x, ln3_g + i*HDIM, ln3_b + i*HDIM, hb);
        for (int ch = 0; ch < 2; ++ch) {
            mgemm_kernel<2><<<gF1, 256, 0, stream>>>(hb + (size_t)ch*HROWS*HDIM, w_f1 + (size_t)i*HF,
                                                     fb1 + i*FDIM, nullptr, tb, nullptr, nullptr, 256, 1024);
            mgemm_kernel<3><<<gF2, 256, 0, stream>>>(tb, w_f2 + (size_t)i*HF,
                                                     fb2 + i*HDIM, x + (size_t)ch*HROWS*HDIM,
                                                     nullptr, nullptr, nullptr, 1024, 256);
        }
    }

    // ---- head ----
    cvt4_kernel<<<NF/4/256, 256, 0, stream>>>(x, hb);
    for (int ch = 0; ch < 2; ++ch) {
        mgemm_kernel<2><<<gF1, 256, 0, stream>>>(hb + (size_t)ch*HROWS*HDIM, w_p1, pb1,
                                                 nullptr, tb, nullptr, nullptr, 256, 1024);
        gemv_head<<<HROWS/4, 256, 0, stream>>>(tb, pW2, pb2, y + (size_t)ch*HROWS);
    }
    final_kernel<<<BDIM*PDIM, 128, 0, stream>>>(y, uW, ub, (float*)d_out);
}